// Round 10
// baseline (254.251 us; speedup 1.0000x reference)
//
#include <hip/hip_runtime.h>

#define HIDDEN 64
#define HALFD  32
#define VOCAB  64
#define BATCH  256
#define SEQLEN 2048

#define WOFF    16384          // float offset of W-pack region in ws
#define WSTRIDE 40             // floats per chunk pack (36 + 4 pad, 16B aligned)

#define RLF(v, sl) __int_as_float(__builtin_amdgcn_readlane(__float_as_int(v), (sl)))
#define RLI(v, sl) __builtin_amdgcn_readlane((v), (sl))
#define GIX(j,m) (((j)==0?0:(j)==1?7:(j)==2?13:(j)==3?18:(j)==4?22:(j)==5?25:27) + (m) - (j) - 1)
#define OM(m) (((m)*((m)+1))>>1)

// ---------------------------------------------------------------------------
// Kernel 1: per-token vocab tables (unchanged).
//   ws[0    ..2047]  ks_voc [64][32]  (normalized hs)
//   ws[2048 ..4095]  ke_voc [64][32]  (normalized he)
//   ws[4096 ..6143]  vs_voc [64][32]  (raw hs)
//   ws[6144 ..8191]  ve_voc [64][32]  (raw he)
//   ws[8192 ..16383] Gs,Ge [2][64][64]
//   ws[16384..]      W-packs [B][2][256][40]   (scan_pre path only)
// ---------------------------------------------------------------------------
__global__ __launch_bounds__(64) void vocab_kernel(
    const float* __restrict__ embed, const float* __restrict__ W1, const float* __restrict__ b1,
    const float* __restrict__ W2, const float* __restrict__ b2,
    const float* __restrict__ ln_g, const float* __restrict__ ln_b,
    const float* __restrict__ Ws, const float* __restrict__ bs,
    const float* __restrict__ We, const float* __restrict__ be,
    float* __restrict__ ws)
{
    const int v = blockIdx.x;
    const int tid = threadIdx.x;

    __shared__ float e_s[64];
    __shared__ float a1_s[128];
    __shared__ float h_s[64];

    e_s[tid] = embed[v * 64 + tid];
    __syncthreads();

    float acc0 = b1[tid], acc1 = b1[tid + 64];
    #pragma unroll 8
    for (int m = 0; m < 64; ++m) {
        float ev = e_s[m];
        acc0 = fmaf(ev, W1[tid * 64 + m], acc0);
        acc1 = fmaf(ev, W1[(tid + 64) * 64 + m], acc1);
    }
    a1_s[tid]      = fmaxf(acc0, 0.0f);
    a1_s[tid + 64] = fmaxf(acc1, 0.0f);
    __syncthreads();

    float ff = b2[tid];
    #pragma unroll 8
    for (int m = 0; m < 128; ++m) ff = fmaf(a1_s[m], W2[tid * 128 + m], ff);
    float x = e_s[tid] + ff;

    float s = x, s2 = x * x;
    #pragma unroll
    for (int off = 32; off >= 1; off >>= 1) {
        s  += __shfl_xor(s,  off, 64);
        s2 += __shfl_xor(s2, off, 64);
    }
    float mu  = s * (1.0f / 64.0f);
    float var = s2 * (1.0f / 64.0f) - mu * mu;
    float hval = (x - mu) * rsqrtf(var + 1e-5f) * ln_g[tid] + ln_b[tid];
    h_s[tid] = hval;
    __syncthreads();

    const int j = tid & 31;
    const bool is_s = tid < 32;
    const float* W = is_s ? Ws : We;
    float acc = is_s ? bs[j] : be[j];
    #pragma unroll 8
    for (int m = 0; m < 64; ++m) acc = fmaf(h_s[m], W[j * 64 + m], acc);

    float n2 = acc * acc;
    #pragma unroll
    for (int off = 16; off >= 1; off >>= 1) n2 += __shfl_xor(n2, off, 64);
    float norm = sqrtf(n2);
    float kn = acc / fmaxf(norm, 1e-12f);

    const int base = v * 32 + j;
    if (is_s) { ws[base]        = kn; ws[4096 + base] = acc; }
    else      { ws[2048 + base] = kn; ws[6144 + base] = acc; }
}

// ---------------------------------------------------------------------------
// Kernel 1b: Gram tables (unchanged).
// ---------------------------------------------------------------------------
__global__ __launch_bounds__(256) void gram_kernel(float* __restrict__ ws)
{
    const int w = blockIdx.x;
    const int tid = threadIdx.x;
    __shared__ float k_s[2048];
    const float* kb = ws + w * 2048;
    for (int i = tid; i < 2048; i += 256) k_s[i] = kb[i];
    __syncthreads();
    const int a  = tid >> 2;
    const int b0 = (tid & 3) << 4;
    float* Gw = ws + 8192 + w * 4096 + a * 64;
    for (int bb = 0; bb < 16; ++bb) {
        const int bcol = b0 + bb;
        float acc = 0.f;
        #pragma unroll
        for (int m = 0; m < 32; ++m) acc = fmaf(k_s[a * 32 + m], k_s[bcol * 32 + m], acc);
        Gw[bcol] = acc;
    }
}

// shared W-build routine (verbatim R9 math)
static __device__ __forceinline__ void build_wpack(
    const int* tj, float fb, float invL, bool is_e, bool is_last, float* Wp,
    const float* __restrict__ Gg)
{
    float f[8];
    #pragma unroll
    for (int j = 0; j < 8; ++j) f[j] = is_e ? (fb + (float)j * invL) : 1.0f;
    if (is_last) f[7] = 0.0f;     // position 2047 is the query, not a write

    float g[28];
    #pragma unroll
    for (int j = 0; j < 7; ++j)
        #pragma unroll
        for (int m = j + 1; m < 8; ++m) g[GIX(j, m)] = Gg[tj[j] * 64 + tj[m]];

    #pragma unroll
    for (int m = 0; m < 8; ++m) {
        float col[8];
        col[m] = f[m];
        #pragma unroll
        for (int j = 6; j >= 0; --j) {
            if (j < m) {
                float acc = 0.0f;
                #pragma unroll
                for (int p = 1; p < 8; ++p)
                    if (p > j && p <= m) acc = fmaf(g[GIX(j, p)], col[p], acc);
                col[j] = -f[j] * acc;
            }
        }
        #pragma unroll
        for (int j = 0; j < 8; ++j)
            if (j <= m) Wp[OM(m) + j] = col[j];
    }
}

struct Chunk {
    int   tokv;      // lane-vector: tok[c*8 + (lane&7)]
    int   tk[8];     // uniform tokens of this chunk
    float grow[8];   // G[tok_j][lane]
    float W[36];     // packed upper-tri solve matrix, col-major: W[OM(m)+j]
};

// ---------------------------------------------------------------------------
// Kernel 2 (primary): Gram-space backward sweep, VMEM-only prefetch.
// R9 post-mortem: W-pack ds_reads share lgkmcnt with the chain's bpermute
// (DS completes in order -> consuming bp drains them), plus both waves fight
// for one DS pipe. Here the ONLY lgkm op in the loop is the bpermute:
//  - W packs built in prologue (R9 math), round-tripped through per-block
//    GLOBAL scratch; loop reads them as uniform global float4s (VMEM).
//  - G rows + token vectors also from global (L1/L2-resident), ping-pong
//    prefetched 1-2 chunks ahead under fine-grained vmcnt.
// ---------------------------------------------------------------------------
__global__ __launch_bounds__(128, 1) void scan_pre_kernel(
    const int* __restrict__ seq, float* __restrict__ ws,
    const float* __restrict__ Wrp, const float* __restrict__ brp,
    const float* __restrict__ Wo, const float* __restrict__ bo,
    float* __restrict__ out)
{
    const int b    = blockIdx.x;
    const int tid  = threadIdx.x;        // 0..127
    const int w    = tid >> 6;           // wave: 0 = s-branch, 1 = e-branch
    const int lane = tid & 63;
    const int l7   = lane & 7;
    const bool is_e = (w == 1);

    __shared__ float wacc_s[2][64];
    __shared__ float r_s[64];
    __shared__ float t1_s[64];

    const float* Gg  = ws + 8192 + w * 4096;
    float*       wsW = ws + WOFF + ((size_t)(b * 2 + w)) * (256 * WSTRIDE);
    const int*   sq  = seq + b * SEQLEN;

    const float invL = 1.0f / (float)SEQLEN;

    // ---- prologue: build all 256 W packs (4 chunks per lane), store global ----
    #pragma unroll
    for (int qq = 0; qq < 4; ++qq) {
        const int c = lane + (qq << 6);
        int tj[8];
        #pragma unroll
        for (int j = 0; j < 8; ++j) tj[j] = sq[c * 8 + j];
        float Wp[36];
        build_wpack(tj, (float)(8 * c + 1) * invL, invL, is_e, c == 255, Wp, Gg);
        float4* dst = (float4*)&wsW[c * WSTRIDE];
        #pragma unroll
        for (int i = 0; i < 9; ++i)
            dst[i] = make_float4(Wp[4*i], Wp[4*i+1], Wp[4*i+2], Wp[4*i+3]);
    }
    __syncthreads();   // drains vmcnt: all W stores visible through L2

    // ---- serial backward sweep ----
    Chunk A, B;
    float u, waccv = 0.0f;

    A.tokv = sq[2040 + l7];
    #pragma unroll
    for (int j = 0; j < 8; ++j) A.tk[j] = RLI(A.tokv, j);
    #pragma unroll
    for (int j = 0; j < 8; ++j) A.grow[j] = Gg[A.tk[j] * 64 + lane];
    {
        const float4* wsrc = (const float4*)&wsW[255 * WSTRIDE];
        #pragma unroll
        for (int i = 0; i < 9; ++i) {
            float4 v = wsrc[i];
            A.W[4*i] = v.x; A.W[4*i+1] = v.y; A.W[4*i+2] = v.z; A.W[4*i+3] = v.w;
        }
    }
    B.tokv = sq[2032 + l7];
    u = Gg[A.tk[7] * 64 + lane];     // query token = position 2047

    auto body = [&](Chunk& cur, Chunk& nxt, int c) {
        // chain anchor: the loop's ONLY lgkm-counted op
        float bp = __shfl(u, cur.tokv, 64);

        // prefetch chunk c-1 (VMEM; independent of the u-chain)
        const int cm1 = (c > 0) ? c - 1 : 0;
        const int cm2 = (c > 1) ? c - 2 : 0;
        #pragma unroll
        for (int j = 0; j < 8; ++j) nxt.tk[j] = RLI(nxt.tokv, j);
        #pragma unroll
        for (int j = 0; j < 8; ++j) nxt.grow[j] = Gg[nxt.tk[j] * 64 + lane];
        {
            const float4* wsrc = (const float4*)&wsW[cm1 * WSTRIDE];
            #pragma unroll
            for (int i = 0; i < 9; ++i) {
                float4 v = wsrc[i];
                nxt.W[4*i] = v.x; nxt.W[4*i+1] = v.y; nxt.W[4*i+2] = v.z; nxt.W[4*i+3] = v.w;
            }
        }
        int tokv2 = sq[cm2 * 8 + l7];

        float t0 = RLF(bp, 0), t1 = RLF(bp, 1), t2 = RLF(bp, 2), t3 = RLF(bp, 3);
        float t4 = RLF(bp, 4), t5 = RLF(bp, 5), t6 = RLF(bp, 6), t7 = RLF(bp, 7);

        // s = W t  (36 independent FMAs, depth <= 4)
        const float* W = cur.W;
        float s7 = W[35] * t7;
        float s6 = fmaf(W[27], t6, W[34] * t7);
        float s5 = fmaf(W[20], t5, W[26] * t6) + W[33] * t7;
        float s4 = fmaf(W[14], t4, W[19] * t5) + fmaf(W[25], t6, W[32] * t7);
        float s3 = fmaf(W[9],  t3, W[13] * t4) + fmaf(W[18], t5, fmaf(W[24], t6, W[31] * t7));
        float s2 = fmaf(W[5],  t2, W[8]  * t3) + fmaf(W[12], t4, W[17] * t5) + fmaf(W[23], t6, W[30] * t7);
        float s1 = fmaf(W[2],  t1, W[4]  * t2) + fmaf(W[7],  t3, W[11] * t4) + fmaf(W[16], t5, fmaf(W[22], t6, W[29] * t7));
        float s0 = fmaf(W[0],  t0, W[1]  * t1) + fmaf(W[3],  t2, W[6]  * t3) + fmaf(W[10], t4, W[15] * t5) + fmaf(W[21], t6, W[28] * t7);

        // u[a] -= sum_j s_j * G[tok_j][a]
        float dA = fmaf(cur.grow[0], s0, fmaf(cur.grow[1], s1, fmaf(cur.grow[2], s2, cur.grow[3] * s3)));
        float dB = fmaf(cur.grow[4], s4, fmaf(cur.grow[5], s5, fmaf(cur.grow[6], s6, cur.grow[7] * s7)));
        u -= (dA + dB);

        // wacc[tok_j] += s_j  (lane = token)
        waccv += (lane == cur.tk[0]) ? s0 : 0.0f;
        waccv += (lane == cur.tk[1]) ? s1 : 0.0f;
        waccv += (lane == cur.tk[2]) ? s2 : 0.0f;
        waccv += (lane == cur.tk[3]) ? s3 : 0.0f;
        waccv += (lane == cur.tk[4]) ? s4 : 0.0f;
        waccv += (lane == cur.tk[5]) ? s5 : 0.0f;
        waccv += (lane == cur.tk[6]) ? s6 : 0.0f;
        waccv += (lane == cur.tk[7]) ? s7 : 0.0f;

        cur.tokv = tokv2;
    };

    for (int c = 255; c >= 1; c -= 2) {
        body(A, B, c);
        body(B, A, c - 1);
    }

    wacc_s[w][lane] = waccv;
    __syncthreads();

    if (tid < 64) {
        const int w2  = tid >> 5;
        const int rho = tid & 31;
        const float* vv = ws + 4096 + w2 * 2048;
        const float* wa = &wacc_s[w2][0];
        float acc = 0.0f;
        #pragma unroll 8
        for (int tok = 0; tok < 64; ++tok) acc = fmaf(wa[tok], vv[tok * 32 + rho], acc);
        r_s[tid] = acc;
    }
    __syncthreads();

    if (tid < 64) {
        float acc = brp[tid];
        #pragma unroll 8
        for (int m = 0; m < 64; ++m) acc = fmaf(Wrp[tid * 64 + m], r_s[m], acc);
        t1_s[tid] = acc;
    }
    __syncthreads();
    if (tid < 64) {
        float acc = bo[tid];
        #pragma unroll 8
        for (int m = 0; m < 64; ++m) acc = fmaf(Wo[tid * 64 + m], t1_s[m], acc);
        out[b * 64 + tid] = acc;
    }
}

// ---------------------------------------------------------------------------
// Kernel 2 (fallback, ws too small for W region): R9 LDS-Wtab version.
// ---------------------------------------------------------------------------
__global__ __launch_bounds__(128) void scan_lds_kernel(
    const int* __restrict__ seq, const float* __restrict__ ws,
    const float* __restrict__ Wrp, const float* __restrict__ brp,
    const float* __restrict__ Wo, const float* __restrict__ bo,
    float* __restrict__ out)
{
    const int b    = blockIdx.x;
    const int tid  = threadIdx.x;
    const int w    = tid >> 6;
    const int lane = tid & 63;
    const int l7   = lane & 7;
    const bool is_e = (w == 1);

    __shared__ __align__(16) float Wtab[2 * 256 * 36];
    __shared__ __align__(16) int   toklds[SEQLEN];
    __shared__ float wacc_s[2][64];
    __shared__ float r_s[64];
    __shared__ float t1_s[64];

    const float* Gg     = ws + 8192 + w * 4096;
    float*       Wtab_w = Wtab + w * (256 * 36);

    {
        const int4* sq4 = (const int4*)(seq + b * SEQLEN);
        int4* tl = (int4*)toklds;
        #pragma unroll
        for (int i = 0; i < 4; ++i) tl[tid + i * 128] = sq4[tid + i * 128];
    }
    __syncthreads();

    {
        const float invL = 1.0f / (float)SEQLEN;
        #pragma unroll
        for (int qq = 0; qq < 4; ++qq) {
            const int c = lane + (qq << 6);
            int tj[8];
            #pragma unroll
            for (int j = 0; j < 8; ++j) tj[j] = toklds[c * 8 + j];
            float Wp[36];
            build_wpack(tj, (float)(8 * c + 1) * invL, invL, is_e, c == 255, Wp, Gg);
            float4* dst = (float4*)&Wtab_w[c * 36];
            #pragma unroll
            for (int i = 0; i < 9; ++i)
                dst[i] = make_float4(Wp[4*i], Wp[4*i+1], Wp[4*i+2], Wp[4*i+3]);
        }
    }
    __syncthreads();

    Chunk A, B;
    float u, waccv = 0.0f;

    A.tokv = toklds[2040 + l7];
    #pragma unroll
    for (int j = 0; j < 8; ++j) A.tk[j] = RLI(A.tokv, j);
    #pragma unroll
    for (int j = 0; j < 8; ++j) A.grow[j] = Gg[A.tk[j] * 64 + lane];
    {
        const float4* wsrc = (const float4*)&Wtab_w[255 * 36];
        #pragma unroll
        for (int i = 0; i < 9; ++i) {
            float4 v = wsrc[i];
            A.W[4*i] = v.x; A.W[4*i+1] = v.y; A.W[4*i+2] = v.z; A.W[4*i+3] = v.w;
        }
    }
    B.tokv = toklds[2032 + l7];
    u = Gg[A.tk[7] * 64 + lane];

    auto body = [&](Chunk& cur, Chunk& nxt, int c) {
        float bp = __shfl(u, cur.tokv, 64);
        const int cm1 = (c > 0) ? c - 1 : 0;
        const int cm2 = (c > 1) ? c - 2 : 0;
        #pragma unroll
        for (int j = 0; j < 8; ++j) nxt.tk[j] = RLI(nxt.tokv, j);
        #pragma unroll
        for (int j = 0; j < 8; ++j) nxt.grow[j] = Gg[nxt.tk[j] * 64 + lane];
        {
            const float4* wsrc = (const float4*)&Wtab_w[cm1 * 36];
            #pragma unroll
            for (int i = 0; i < 9; ++i) {
                float4 v = wsrc[i];
                nxt.W[4*i] = v.x; nxt.W[4*i+1] = v.y; nxt.W[4*i+2] = v.z; nxt.W[4*i+3] = v.w;
            }
        }
        int tokv2 = toklds[cm2 * 8 + l7];

        float t0 = RLF(bp, 0), t1 = RLF(bp, 1), t2 = RLF(bp, 2), t3 = RLF(bp, 3);
        float t4 = RLF(bp, 4), t5 = RLF(bp, 5), t6 = RLF(bp, 6), t7 = RLF(bp, 7);

        const float* W = cur.W;
        float s7 = W[35] * t7;
        float s6 = fmaf(W[27], t6, W[34] * t7);
        float s5 = fmaf(W[20], t5, W[26] * t6) + W[33] * t7;
        float s4 = fmaf(W[14], t4, W[19] * t5) + fmaf(W[25], t6, W[32] * t7);
        float s3 = fmaf(W[9],  t3, W[13] * t4) + fmaf(W[18], t5, fmaf(W[24], t6, W[31] * t7));
        float s2 = fmaf(W[5],  t2, W[8]  * t3) + fmaf(W[12], t4, W[17] * t5) + fmaf(W[23], t6, W[30] * t7);
        float s1 = fmaf(W[2],  t1, W[4]  * t2) + fmaf(W[7],  t3, W[11] * t4) + fmaf(W[16], t5, fmaf(W[22], t6, W[29] * t7));
        float s0 = fmaf(W[0],  t0, W[1]  * t1) + fmaf(W[3],  t2, W[6]  * t3) + fmaf(W[10], t4, W[15] * t5) + fmaf(W[21], t6, W[28] * t7);

        float dA = fmaf(cur.grow[0], s0, fmaf(cur.grow[1], s1, fmaf(cur.grow[2], s2, cur.grow[3] * s3)));
        float dB = fmaf(cur.grow[4], s4, fmaf(cur.grow[5], s5, fmaf(cur.grow[6], s6, cur.grow[7] * s7)));
        u -= (dA + dB);

        waccv += (lane == cur.tk[0]) ? s0 : 0.0f;
        waccv += (lane == cur.tk[1]) ? s1 : 0.0f;
        waccv += (lane == cur.tk[2]) ? s2 : 0.0f;
        waccv += (lane == cur.tk[3]) ? s3 : 0.0f;
        waccv += (lane == cur.tk[4]) ? s4 : 0.0f;
        waccv += (lane == cur.tk[5]) ? s5 : 0.0f;
        waccv += (lane == cur.tk[6]) ? s6 : 0.0f;
        waccv += (lane == cur.tk[7]) ? s7 : 0.0f;

        cur.tokv = tokv2;
    };

    for (int c = 255; c >= 1; c -= 2) {
        body(A, B, c);
        body(B, A, c - 1);
    }

    wacc_s[w][lane] = waccv;
    __syncthreads();

    if (tid < 64) {
        const int w2  = tid >> 5;
        const int rho = tid & 31;
        const float* vv = ws + 4096 + w2 * 2048;
        const float* wa = &wacc_s[w2][0];
        float acc = 0.0f;
        #pragma unroll 8
        for (int tok = 0; tok < 64; ++tok) acc = fmaf(wa[tok], vv[tok * 32 + rho], acc);
        r_s[tid] = acc;
    }
    __syncthreads();

    if (tid < 64) {
        float acc = brp[tid];
        #pragma unroll 8
        for (int m = 0; m < 64; ++m) acc = fmaf(Wrp[tid * 64 + m], r_s[m], acc);
        t1_s[tid] = acc;
    }
    __syncthreads();
    if (tid < 64) {
        float acc = bo[tid];
        #pragma unroll 8
        for (int m = 0; m < 64; ++m) acc = fmaf(Wo[tid * 64 + m], t1_s[m], acc);
        out[b * 64 + tid] = acc;
    }
}

extern "C" void kernel_launch(void* const* d_in, const int* in_sizes, int n_in,
                              void* d_out, int out_size, void* d_ws, size_t ws_size,
                              hipStream_t stream)
{
    const int*   seq   = (const int*)  d_in[0];
    const float* embed = (const float*)d_in[1];
    const float* W1    = (const float*)d_in[2];
    const float* b1    = (const float*)d_in[3];
    const float* W2    = (const float*)d_in[4];
    const float* b2    = (const float*)d_in[5];
    const float* ln_g  = (const float*)d_in[6];
    const float* ln_b  = (const float*)d_in[7];
    const float* Ws    = (const float*)d_in[8];
    const float* bs    = (const float*)d_in[9];
    const float* We    = (const float*)d_in[10];
    const float* be    = (const float*)d_in[11];
    const float* Wrp   = (const float*)d_in[12];
    const float* brp   = (const float*)d_in[13];
    const float* Wo    = (const float*)d_in[14];
    const float* bo    = (const float*)d_in[15];
    float* ws  = (float*)d_ws;
    float* out = (float*)d_out;

    hipLaunchKernelGGL(vocab_kernel, dim3(VOCAB), dim3(64), 0, stream,
                       embed, W1, b1, W2, b2, ln_g, ln_b, Ws, bs, We, be, ws);
    hipLaunchKernelGGL(gram_kernel, dim3(2), dim3(256), 0, stream, ws);

    const size_t need = (size_t)(WOFF + BATCH * 2 * 256 * WSTRIDE) * sizeof(float);
    if (ws_size >= need) {
        hipLaunchKernelGGL(scan_pre_kernel, dim3(BATCH), dim3(128), 0, stream,
                           seq, ws, Wrp, brp, Wo, bo, out);
    } else {
        hipLaunchKernelGGL(scan_lds_kernel, dim3(BATCH), dim3(128), 0, stream,
                           seq, ws, Wrp, brp, Wo, bo, out);
    }
}